// Round 8
// baseline (740.170 us; speedup 1.0000x reference)
//
#include <hip/hip_runtime.h>

// LightGCN single forward, round 8.
// CSR build with (row, column-segment) counting sort + cohort-phased pull-SpMM:
// all waves co-resident, looping column segments in lockstep so each 2MB fp8
// table slice is L2-resident while it is being gathered. Row accumulators live
// in registers across all segments (no partial-sum traffic).
//
// d_out: [0,ND) light_out (acc until layer 3), [ND,2ND) user‖item copies.

#define NUM_USER 100000
#define NUM_ITEM 50000
#define NTOT     150000
#define DIM      64
#define NEDGE    2400000
#define ND       (NTOT * DIM)

#define RPB    256                       // rows per bucket
#define NB     586                       // ceil(NTOT/RPB)
#define CAP    4736                      // slots/bucket: mean 4096 + 10 sigma
#define CHUNK  4096                      // edges per phaseA block
#define NCHUNK 586                       // ceil(NEDGE/CHUNK)
#define EPT    16                        // CHUNK/256
#define CVTB   1024                      // extra phaseA blocks doing f32->fp8

#define NSEG   5                         // column segments (col >> 15)
#define NKEY   2048                      // RPB * 8 (seg field padded to 3 bits)
#define RW     37                        // rows per wave (cohort)
#define COHORT_BLOCKS 1014               // ceil(150000 / (37*4)) — all resident

typedef float v2f __attribute__((ext_vector_type(2)));

// 4 f32 -> packed 4×fp8 e4m3 (HW RNE, saturating)
static __device__ __forceinline__ unsigned pk_fp8x4(float a, float b, float c, float d) {
    int p = 0;
    p = __builtin_amdgcn_cvt_pk_fp8_f32(a, b, p, false);
    p = __builtin_amdgcn_cvt_pk_fp8_f32(c, d, p, true);
    return (unsigned)p;
}
static __device__ __forceinline__ unsigned char f2fp8(float a) {
    return (unsigned char)(__builtin_amdgcn_cvt_pk_fp8_f32(a, 0.f, 0, false) & 0xFF);
}

// ---- Phase A: bin edges into 586 row-buckets; blocks >= NCHUNK convert
//      the f32 embeddings to the fp8(16x) x-table (independent, overlapped) ----
__global__ __launch_bounds__(256) void phaseA_kernel(
    const int*   __restrict__ rows,
    const int*   __restrict__ cols,
    const float* __restrict__ vals,
    int*            __restrict__ cursor,  // per-bucket fill count (memset 0)
    unsigned*       __restrict__ crG,     // packed (rowlow8<<18)|col18, bucketed
    unsigned short* __restrict__ vbG,     // fp8(64*val) in low byte, bucketed
    const float*    __restrict__ user,
    const float*    __restrict__ item,
    unsigned*       __restrict__ xq)      // fp8 table as u32 words
{
    __shared__ unsigned       s_cr[CHUNK];
    __shared__ unsigned short s_vb[CHUNK];
    __shared__ unsigned short s_bk[CHUNK];
    __shared__ int s_hist[NB];
    __shared__ int s_scan[NB];
    __shared__ int s_dst[NB];
    __shared__ int s_cur[NB];
    __shared__ int s_part[256];

    if (blockIdx.x >= NCHUNK) {
        // fused convert: all_emb (f32) -> fp8(16*x) table (u32 = 4 dims)
        const int nvec  = ND / 4;
        const int userv = NUM_USER * DIM / 4;
        for (int i = (blockIdx.x - NCHUNK) * 256 + threadIdx.x; i < nvec;
             i += CVTB * 256) {
            const float4 v = (i < userv) ? ((const float4*)user)[i]
                                         : ((const float4*)item)[i - userv];
            xq[i] = pk_fp8x4(v.x * 16.f, v.y * 16.f, v.z * 16.f, v.w * 16.f);
        }
        return;
    }

    const int t    = threadIdx.x;
    const int base = blockIdx.x * CHUNK;
    const int n    = min(CHUNK, NEDGE - base);

    for (int i = t; i < NB; i += 256) s_hist[i] = 0;
    __syncthreads();

    int            mrow[EPT];
    unsigned       mcol[EPT];
    unsigned short mvb[EPT];
#pragma unroll
    for (int k = 0; k < EPT; ++k) {
        const int i = t + k * 256;
        if (i < n) {
            const int e = base + i;
            mrow[k] = rows[e];
            mcol[k] = (unsigned)cols[e];
            mvb[k]  = f2fp8(vals[e] * 64.f);
            atomicAdd(&s_hist[mrow[k] >> 8], 1);
        } else mrow[k] = -1;
    }
    __syncthreads();

    // exclusive scan of s_hist[0..NB)
    int loc[3]; int ssum = 0;
#pragma unroll
    for (int k = 0; k < 3; ++k) {
        const int i = t * 3 + k;
        loc[k] = (i < NB) ? s_hist[i] : 0;
        ssum += loc[k];
    }
    s_part[t] = ssum;
    __syncthreads();
    for (int o = 1; o < 256; o <<= 1) {
        const int v = (t >= o) ? s_part[t - o] : 0;
        __syncthreads();
        s_part[t] += v;
        __syncthreads();
    }
    int run = s_part[t] - ssum;
#pragma unroll
    for (int k = 0; k < 3; ++k) {
        const int i = t * 3 + k;
        if (i < NB) { s_scan[i] = run; run += loc[k]; }
    }
    __syncthreads();

    for (int i = t; i < NB; i += 256) {
        const int c = s_hist[i];
        s_dst[i] = i * CAP + (c ? atomicAdd(&cursor[i], c) : 0);
        s_cur[i] = s_scan[i];
    }
    __syncthreads();

#pragma unroll
    for (int k = 0; k < EPT; ++k) {
        if (mrow[k] >= 0) {
            const int b   = mrow[k] >> 8;
            const int pos = atomicAdd(&s_cur[b], 1);
            s_cr[pos] = mcol[k] | ((unsigned)(mrow[k] & 255) << 18);
            s_vb[pos] = mvb[k];
            s_bk[pos] = (unsigned short)b;
        }
    }
    __syncthreads();

    for (int p = t; p < n; p += 256) {
        const int b = s_bk[p];
        const int g = s_dst[b] + (p - s_scan[b]);
        crG[g] = s_cr[p];
        vbG[g] = s_vb[p];
    }
}

// ---- Phase B: per-bucket in-LDS counting sort by (row, colseg);
//      writeback converts to (col<<8)|fp8val; emit per-(row,seg) ranges ----
__global__ __launch_bounds__(256) void phaseB_kernel(
    const int*      __restrict__ cursor,
    unsigned*       __restrict__ crG,
    const unsigned short* __restrict__ vbG,
    int2*           __restrict__ segbe)   // [NTOT*8] (beg, end)
{
    __shared__ unsigned       s_cr[CAP];
    __shared__ unsigned short s_vb[CAP];
    __shared__ unsigned short s_idx[CAP];
    __shared__ int s_hist[NKEY];          // counts -> exclusive prefix
    __shared__ int s_cur[NKEY];
    __shared__ int s_part[256];

    const int b = blockIdx.x, t = threadIdx.x;
    const int gbase = b * CAP;
    const int cnt = cursor[b];

    for (int i = t; i < NKEY; i += 256) s_hist[i] = 0;
    __syncthreads();
    for (int p = t; p < cnt; p += 256) {
        const unsigned cr = crG[gbase + p];
        s_cr[p] = cr;
        s_vb[p] = vbG[gbase + p];
        const int key = (int)(((cr >> 18) << 3) | ((cr >> 15) & 7u));
        atomicAdd(&s_hist[key], 1);
    }
    __syncthreads();

    // exclusive scan over 2048 keys: 8 keys/thread + Hillis-Steele on partials
    int loc[8]; int ssum = 0;
#pragma unroll
    for (int j = 0; j < 8; ++j) { loc[j] = s_hist[t * 8 + j]; ssum += loc[j]; }
    s_part[t] = ssum;
    __syncthreads();
    for (int o = 1; o < 256; o <<= 1) {
        const int v = (t >= o) ? s_part[t - o] : 0;
        __syncthreads();
        s_part[t] += v;
        __syncthreads();
    }
    int run = s_part[t] - ssum;
    __syncthreads();
#pragma unroll
    for (int j = 0; j < 8; ++j) {
        s_hist[t * 8 + j] = run;          // exclusive prefix (kept for segbe)
        s_cur[t * 8 + j]  = run;
        run += loc[j];
    }
    __syncthreads();

    for (int p = t; p < cnt; p += 256) {
        const unsigned cr = s_cr[p];
        const int key = (int)(((cr >> 18) << 3) | ((cr >> 15) & 7u));
        const int pos = atomicAdd(&s_cur[key], 1);
        s_idx[pos] = (unsigned short)p;
    }
    __syncthreads();

    for (int p = t; p < cnt; p += 256) {
        const int i = s_idx[p];
        // SpMM metadata: (col18 << 8) | fp8(64*val)
        crG[gbase + p] = ((s_cr[i] & 0x3FFFFu) << 8) | (unsigned)(s_vb[i] & 0xFFu);
    }
    __syncthreads();

    // emit (beg,end) per (row, seg); s_cur[key] == excl + count now
    for (int i = t; i < NKEY; i += 256) {
        const int row = b * RPB + (i >> 3);
        if (row < NTOT)
            segbe[(row << 3) | (i & 7)] =
                make_int2(gbase + s_hist[i], gbase + s_cur[i]);
    }
}

// ---- cohort pull-SpMM: grid = 1014 blocks, all waves resident.
//      Wave owns RW consecutive rows; acc in registers across all segments.
//      Lane layout: 2 edge groups (g = lane>>5) × 32 lanes × 2 dims.
// MODE 0: acc=res, destq=fp8(16*res)
// MODE 1: acc+=res, destq=fp8(16*res)
// MODE 2: light_out=(acc+res+ae)/4, out2=ae   (finalize fused)
template<int MODE>
__global__ __launch_bounds__(256, 4) void spmm_cohort(
    const int2*           __restrict__ segbe,
    const unsigned*       __restrict__ cv,      // (col<<8)|fp8v
    const unsigned char*  __restrict__ xq,      // fp8 table (row = 64 B)
    unsigned char*        __restrict__ destq,   // fp8 next-layer table
    float*                __restrict__ acc,
    const float*          __restrict__ user,
    const float*          __restrict__ item,
    float*                __restrict__ out)
{
    const int wave = ((blockIdx.x << 8) + threadIdx.x) >> 6;
    const int lane = threadIdx.x & 63;
    const int g    = lane >> 5;              // edge parity group
    const int l2   = (lane & 31) << 1;       // dims l2, l2+1
    const int r0   = wave * RW;

    v2f a[RW];
#pragma unroll
    for (int i = 0; i < RW; ++i) a[i] = (v2f){0.f, 0.f};

    for (int s = 0; s < NSEG; ++s) {
#pragma unroll
        for (int i = 0; i < RW; ++i) {
            const int r = r0 + i;
            if (r < NTOT) {
                const int2 be = segbe[(r << 3) | s];
                for (int k = be.x; k < be.y; k += 4) {
                    const int kend = be.y - 1;
                    const int ka = k + g;
                    const int kb = k + 2 + g;
                    unsigned ca = cv[min(ka, kend)];
                    unsigned cb = cv[min(kb, kend)];
                    if (ka > kend) ca = 0u;          // val byte 0 -> contributes 0
                    if (kb > kend) cb = 0u;
                    const v2f va = __builtin_amdgcn_cvt_pk_f32_fp8((int)ca, false);
                    const v2f vb = __builtin_amdgcn_cvt_pk_f32_fp8((int)cb, false);
                    const unsigned offa = ((ca & 0xFFFFFF00u) >> 2) + l2;  // col*64+l2
                    const unsigned offb = ((cb & 0xFFFFFF00u) >> 2) + l2;
                    const unsigned short wa = *(const unsigned short*)(xq + offa);
                    const unsigned short wb = *(const unsigned short*)(xq + offb);
                    const v2f xa = __builtin_amdgcn_cvt_pk_f32_fp8((int)(unsigned)wa, false);
                    const v2f xb = __builtin_amdgcn_cvt_pk_f32_fp8((int)(unsigned)wb, false);
                    a[i] += (v2f){va[0], va[0]} * xa;
                    a[i] += (v2f){vb[0], vb[0]} * xb;
                }
            }
        }
    }

    const float sc = 1.f / 1024.f;           // undo x*16 and v*64
#pragma unroll
    for (int i = 0; i < RW; ++i) {
        const int r = r0 + i;
        if (r >= NTOT) continue;
        float f0 = a[i][0], f1 = a[i][1];
        f0 += __shfl_xor(f0, 32);
        f1 += __shfl_xor(f1, 32);
        f0 *= sc; f1 *= sc;
        if (lane < 32) {
            const int o = (r << 6) + l2;
            if (MODE == 0) {
                *(float2*)(acc + o) = make_float2(f0, f1);
            } else if (MODE == 1) {
                float2 tch = *(float2*)(acc + o);
                tch.x += f0; tch.y += f1;
                *(float2*)(acc + o) = tch;
            } else {
                const float* aep = (r < NUM_USER)
                    ? user + ((size_t)r << 6) + l2
                    : item + ((size_t)(r - NUM_USER) << 6) + l2;
                const float2 ae = *(const float2*)aep;
                const float2 tch = *(const float2*)(acc + o);
                *(float2*)(out + o) =
                    make_float2((tch.x + f0 + ae.x) * 0.25f,
                                (tch.y + f1 + ae.y) * 0.25f);
                *(float2*)(out + ND + o) = ae;
            }
            if (MODE != 2) {
                const unsigned p = pk_fp8x4(f0 * 16.f, f1 * 16.f, 0.f, 0.f);
                *(unsigned short*)(destq + o) = (unsigned short)(p & 0xFFFFu);
            }
        }
    }
}

// ---------------- fallback (round-1 atomic path) ----------------

__global__ __launch_bounds__(256) void spmm_atomic(
    const float* __restrict__ vals, const int* __restrict__ rows,
    const int* __restrict__ cols, const float* __restrict__ x0,
    const float* __restrict__ x1, int split, float* __restrict__ out)
{
    const int lane = threadIdx.x & 63;
    const long wave   = ((long)blockIdx.x * blockDim.x + threadIdx.x) >> 6;
    const long nwaves = ((long)gridDim.x * blockDim.x) >> 6;
    for (long e = wave; e < NEDGE; e += nwaves) {
        const int   r = rows[e];
        const int   c = cols[e];
        const float v = vals[e];
        const float xv = (c < split) ? x0[(long)c * DIM + lane]
                                     : x1[(long)(c - split) * DIM + lane];
        atomicAdd(&out[(long)r * DIM + lane], v * xv);
    }
}

__global__ __launch_bounds__(256) void add2_kernel(
    const float* __restrict__ a, const float* __restrict__ b,
    float* __restrict__ acc)
{
    const int nvec = ND / 4;
    for (int i = blockIdx.x * blockDim.x + threadIdx.x; i < nvec;
         i += gridDim.x * blockDim.x) {
        const float4 av = ((const float4*)a)[i];
        const float4 bv = ((const float4*)b)[i];
        float4 o;
        o.x = av.x + bv.x; o.y = av.y + bv.y;
        o.z = av.z + bv.z; o.w = av.w + bv.w;
        ((float4*)acc)[i] = o;
    }
}

__global__ __launch_bounds__(256) void finalize3_kernel(
    const float* __restrict__ user, const float* __restrict__ item,
    float* __restrict__ out)
{
    const int nvec  = ND / 4;
    const int userv = NUM_USER * DIM / 4;
    for (int i = blockIdx.x * blockDim.x + threadIdx.x; i < nvec;
         i += gridDim.x * blockDim.x) {
        const float4 ae = (i < userv) ? ((const float4*)user)[i]
                                      : ((const float4*)item)[i - userv];
        const float4 ac = ((const float4*)out)[i];
        const float4 e3 = ((const float4*)(out + ND))[i];
        float4 lo;
        lo.x = (ae.x + ac.x + e3.x) * 0.25f;
        lo.y = (ae.y + ac.y + e3.y) * 0.25f;
        lo.z = (ae.z + ac.z + e3.z) * 0.25f;
        lo.w = (ae.w + ac.w + e3.w) * 0.25f;
        ((float4*)out)[i] = lo;
        ((float4*)(out + ND))[i] = ae;
    }
}

// ---------------- launch ----------------

extern "C" void kernel_launch(void* const* d_in, const int* in_sizes, int n_in,
                              void* d_out, int out_size, void* d_ws, size_t ws_size,
                              hipStream_t stream) {
    const float* user = (const float*)d_in[0];
    const float* item = (const float*)d_in[1];
    const float* vals = (const float*)d_in[2];
    const int*   rows = (const int*)d_in[3];
    const int*   cols = (const int*)d_in[4];

    float* out = (float*)d_out;
    float* acc = out;

    char* w = (char*)d_ws;
    unsigned char* xq0 = (unsigned char*)w;                         // ND fp8
    unsigned char* xq1 = xq0 + ND;                                  // ND fp8
    unsigned*      crG = (unsigned*)(xq1 + ND);                     // NB*CAP u32
    unsigned short* vbG = (unsigned short*)(crG + (size_t)NB * CAP);// NB*CAP u16
    int2*  segbe  = (int2*)(vbG + (size_t)NB * CAP);                // NTOT*8 int2
    int*   cursor = (int*)(segbe + (size_t)NTOT * 8);               // NB
    const size_t ws_need = (size_t)ND * 2 + (size_t)NB * CAP * 6
                         + (size_t)NTOT * 8 * 8 + (size_t)NB * 4 + 64;

    if (ws_size >= ws_need) {
        hipMemsetAsync(cursor, 0, (size_t)NB * 4, stream);
        phaseA_kernel<<<NCHUNK + CVTB, 256, 0, stream>>>(
            rows, cols, vals, cursor, crG, vbG, user, item, (unsigned*)xq0);
        phaseB_kernel<<<NB, 256, 0, stream>>>(cursor, crG, vbG, segbe);

        spmm_cohort<0><<<COHORT_BLOCKS, 256, 0, stream>>>(segbe, crG,
            xq0, xq1, acc, nullptr, nullptr, nullptr);               // emb1
        spmm_cohort<1><<<COHORT_BLOCKS, 256, 0, stream>>>(segbe, crG,
            xq1, xq0, acc, nullptr, nullptr, nullptr);               // emb2
        spmm_cohort<2><<<COHORT_BLOCKS, 256, 0, stream>>>(segbe, crG,
            xq0, nullptr, acc, user, item, out);                     // emb3+finalize
    } else {
        float* bufA = (float*)d_ws;
        float* out1 = out + ND;
        const size_t nd_bytes = (size_t)ND * sizeof(float);
        hipMemsetAsync(out1, 0, nd_bytes, stream);
        spmm_atomic<<<2048, 256, 0, stream>>>(vals, rows, cols, user, item, NUM_USER, out1);
        hipMemsetAsync(bufA, 0, nd_bytes, stream);
        spmm_atomic<<<2048, 256, 0, stream>>>(vals, rows, cols, out1, out1, NTOT, bufA);
        add2_kernel<<<2048, 256, 0, stream>>>(out1, bufA, acc);
        hipMemsetAsync(out1, 0, nd_bytes, stream);
        spmm_atomic<<<2048, 256, 0, stream>>>(vals, rows, cols, bufA, bufA, NTOT, out1);
        finalize3_kernel<<<2048, 256, 0, stream>>>(user, item, out);
    }
}

// Round 9
// 336.362 us; speedup vs baseline: 2.2005x; 2.2005x over previous
//
#include <hip/hip_runtime.h>

// LightGCN single forward, round 9.
// R7 CSR build + R7-structure pull-SpMM, but the fp8 table is stored
// HALF-MAJOR (32 dims of all rows contiguous = 4.8 MB) and each layer runs as
// two dispatches, one per dim-half. Per dispatch the gather working set is
// ~4.8 MB ~= per-XCD L2, so gathers become L2 hits instead of LLC round-trips.
// Edge loop keeps 16 independent gathers in flight per wave (R8 lesson).
//
// d_out: [0,ND) light_out (acc until layer 3), [ND,2ND) user‖item copies.

#define NUM_USER 100000
#define NUM_ITEM 50000
#define NTOT     150000
#define DIM      64
#define NEDGE    2400000
#define ND       (NTOT * DIM)
#define HWORDS   (NTOT * 8)              // dwords per half-table

#define RPB    256                       // rows per bucket
#define NB     586                       // ceil(NTOT/RPB)
#define CAP    4736                      // slots/bucket: mean 4096 + 10 sigma
#define CHUNK  4096                      // edges per phaseA block
#define NCHUNK 586                       // ceil(NEDGE/CHUNK)
#define EPT    16                        // CHUNK/256
#define CVTB   1024                      // extra phaseA blocks doing f32->fp8

typedef float v2f __attribute__((ext_vector_type(2)));

// 4 f32 -> packed 4×fp8 e4m3 (HW RNE, saturating)
static __device__ __forceinline__ unsigned pk_fp8x4(float a, float b, float c, float d) {
    int p = 0;
    p = __builtin_amdgcn_cvt_pk_fp8_f32(a, b, p, false);
    p = __builtin_amdgcn_cvt_pk_fp8_f32(c, d, p, true);
    return (unsigned)p;
}
static __device__ __forceinline__ unsigned char f2fp8(float a) {
    return (unsigned char)(__builtin_amdgcn_cvt_pk_fp8_f32(a, 0.f, 0, false) & 0xFF);
}
// decode low byte of word -> f32
static __device__ __forceinline__ float fp8lo2f(unsigned w) {
    const v2f t = __builtin_amdgcn_cvt_pk_f32_fp8((int)w, false);
    return t[0];
}

// ---- Phase A: bin edges into 586 row-buckets; blocks >= NCHUNK convert
//      the f32 embeddings to the fp8(16x) HALF-MAJOR table ----
__global__ __launch_bounds__(256) void phaseA_kernel(
    const int*   __restrict__ rows,
    const int*   __restrict__ cols,
    const float* __restrict__ vals,
    int*            __restrict__ cursor,  // per-bucket fill count (memset 0)
    unsigned*       __restrict__ crG,     // packed (rowlow8<<18)|col18, bucketed
    unsigned short* __restrict__ vbG,     // fp8(64*val) in low byte, bucketed
    const float*    __restrict__ user,
    const float*    __restrict__ item,
    unsigned*       __restrict__ xq)      // fp8 table, half-major, u32 words
{
    __shared__ unsigned       s_cr[CHUNK];
    __shared__ unsigned short s_vb[CHUNK];
    __shared__ unsigned short s_bk[CHUNK];
    __shared__ int s_hist[NB];
    __shared__ int s_scan[NB];
    __shared__ int s_dst[NB];
    __shared__ int s_cur[NB];
    __shared__ int s_part[256];

    if (blockIdx.x >= NCHUNK) {
        // convert: input dword i = dims [4*(i&15)..] of row i>>4
        // output half-major: h = (i>>3)&1, j = i&7 -> xq[h*HWORDS + row*8 + j]
        const int nvec  = ND / 4;
        const int userv = NUM_USER * DIM / 4;
        for (int i = (blockIdx.x - NCHUNK) * 256 + threadIdx.x; i < nvec;
             i += CVTB * 256) {
            const float4 v = (i < userv) ? ((const float4*)user)[i]
                                         : ((const float4*)item)[i - userv];
            const int row = i >> 4, h = (i >> 3) & 1, j = i & 7;
            xq[h * HWORDS + row * 8 + j] =
                pk_fp8x4(v.x * 16.f, v.y * 16.f, v.z * 16.f, v.w * 16.f);
        }
        return;
    }

    const int t    = threadIdx.x;
    const int base = blockIdx.x * CHUNK;
    const int n    = min(CHUNK, NEDGE - base);

    for (int i = t; i < NB; i += 256) s_hist[i] = 0;
    __syncthreads();

    int            mrow[EPT];
    unsigned       mcol[EPT];
    unsigned short mvb[EPT];
#pragma unroll
    for (int k = 0; k < EPT; ++k) {
        const int i = t + k * 256;
        if (i < n) {
            const int e = base + i;
            mrow[k] = rows[e];
            mcol[k] = (unsigned)cols[e];
            mvb[k]  = f2fp8(vals[e] * 64.f);
            atomicAdd(&s_hist[mrow[k] >> 8], 1);
        } else mrow[k] = -1;
    }
    __syncthreads();

    // exclusive scan of s_hist[0..NB)
    int loc[3]; int ssum = 0;
#pragma unroll
    for (int k = 0; k < 3; ++k) {
        const int i = t * 3 + k;
        loc[k] = (i < NB) ? s_hist[i] : 0;
        ssum += loc[k];
    }
    s_part[t] = ssum;
    __syncthreads();
    for (int o = 1; o < 256; o <<= 1) {
        const int v = (t >= o) ? s_part[t - o] : 0;
        __syncthreads();
        s_part[t] += v;
        __syncthreads();
    }
    int run = s_part[t] - ssum;
#pragma unroll
    for (int k = 0; k < 3; ++k) {
        const int i = t * 3 + k;
        if (i < NB) { s_scan[i] = run; run += loc[k]; }
    }
    __syncthreads();

    for (int i = t; i < NB; i += 256) {
        const int c = s_hist[i];
        s_dst[i] = i * CAP + (c ? atomicAdd(&cursor[i], c) : 0);
        s_cur[i] = s_scan[i];
    }
    __syncthreads();

#pragma unroll
    for (int k = 0; k < EPT; ++k) {
        if (mrow[k] >= 0) {
            const int b   = mrow[k] >> 8;
            const int pos = atomicAdd(&s_cur[b], 1);
            s_cr[pos] = mcol[k] | ((unsigned)(mrow[k] & 255) << 18);
            s_vb[pos] = mvb[k];
            s_bk[pos] = (unsigned short)b;
        }
    }
    __syncthreads();

    for (int p = t; p < n; p += 256) {
        const int b = s_bk[p];
        const int g = s_dst[b] + (p - s_scan[b]);
        crG[g] = s_cr[p];
        vbG[g] = s_vb[p];
    }
}

// ---- Phase B: per-bucket in-LDS counting sort by row; writeback converts
//      to the SpMM format (col<<8)|fp8val; emit rowbeg/rowend ----
__global__ __launch_bounds__(256) void phaseB_kernel(
    const int*      __restrict__ cursor,
    unsigned*       __restrict__ crG,
    const unsigned short* __restrict__ vbG,
    int*            __restrict__ rowbeg,
    int*            __restrict__ rowend)
{
    __shared__ unsigned       s_cr[CAP];
    __shared__ unsigned short s_vb[CAP];
    __shared__ unsigned short s_idx[CAP];
    __shared__ int s_hist[RPB];
    __shared__ int s_scan[RPB];
    __shared__ int s_cur[RPB];

    const int b = blockIdx.x, t = threadIdx.x;
    const int gbase = b * CAP;
    const int cnt = cursor[b];

    s_hist[t] = 0;
    __syncthreads();
    for (int p = t; p < cnt; p += 256) {
        const unsigned cr = crG[gbase + p];
        s_cr[p] = cr;
        s_vb[p] = vbG[gbase + p];
        atomicAdd(&s_hist[cr >> 18], 1);
    }
    __syncthreads();

    const int h = s_hist[t];
    s_scan[t] = h;
    __syncthreads();
    for (int o = 1; o < 256; o <<= 1) {
        const int v = (t >= o) ? s_scan[t - o] : 0;
        __syncthreads();
        s_scan[t] += v;
        __syncthreads();
    }
    const int excl = s_scan[t] - h;
    s_cur[t] = excl;
    __syncthreads();

    for (int p = t; p < cnt; p += 256) {
        const int r   = s_cr[p] >> 18;
        const int pos = atomicAdd(&s_cur[r], 1);
        s_idx[pos] = (unsigned short)p;
    }
    __syncthreads();

    for (int p = t; p < cnt; p += 256) {
        const int i = s_idx[p];
        // SpMM metadata format: (col18 << 8) | fp8(64*val)
        crG[gbase + p] = ((s_cr[i] & 0x3FFFFu) << 8) | (unsigned)(s_vb[i] & 0xFFu);
    }
    const int row = b * RPB + t;
    if (row < NTOT) {
        rowbeg[row] = gbase + excl;
        rowend[row] = gbase + excl + h;
    }
}

// ---- pull SpMM, one dim-half per dispatch.
//      One wave/row, 8 edge groups × 2-deep unroll (16 gathers in flight).
//      Lane reads 4 fp8 dims (dword) from half-table H; one u32 metadata/edge.
//      Scales: x stored *16, v stored *64 -> result * 2^-10.
// MODE 0: acc=res, destq=fp8(16*res)
// MODE 1: acc+=res, destq=fp8(16*res)
// MODE 2: light_out=(acc+res+ae)/4, out2=ae   (finalize fused)
template<int MODE, int H>
__global__ __launch_bounds__(256) void spmm_pull(
    const int*            __restrict__ rowbeg,
    const int*            __restrict__ rowend,
    const unsigned*       __restrict__ cv,      // (col<<8)|fp8v
    const unsigned char*  __restrict__ xq,      // fp8 table base (half-major)
    unsigned*             __restrict__ destq,   // fp8 out (u32, half-major)
    float*                __restrict__ acc,
    const float*          __restrict__ user,
    const float*          __restrict__ item,
    float*                __restrict__ out)
{
    const int r    = (blockIdx.x * 256 + threadIdx.x) >> 6;  // grid sized exactly
    const int lane = threadIdx.x & 63;
    const int g    = lane >> 3;          // edge group 0..7
    const int l    = lane & 7;           // lane-in-group: dims 4l..4l+3 of half

    const int beg = __builtin_amdgcn_readfirstlane(rowbeg[r]);
    const int end = __builtin_amdgcn_readfirstlane(rowend[r]);

    const unsigned char* xh = xq + (size_t)H * (HWORDS * 4);

    v2f a0 = {0.f,0.f}, a1 = {0.f,0.f};
    for (int k = beg + g; k < end; k += 16) {
        const bool h1 = (k + 8) < end;
        const int  kb = h1 ? k + 8 : k;          // clamped: always valid
        const unsigned ca = cv[k];
        unsigned cb = cv[kb];
        cb = h1 ? cb : (cb & ~0xFFu);            // zero val byte on tail

        const float va = fp8lo2f(ca);
        const float vb = fp8lo2f(cb);

        const unsigned offA = ((ca & 0xFFFFFF00u) >> 3) + (l << 2);  // col*32+l*4
        const unsigned offB = ((cb & 0xFFFFFF00u) >> 3) + (l << 2);
        const unsigned wa = *reinterpret_cast<const unsigned*>(xh + offA);
        const unsigned wb = *reinterpret_cast<const unsigned*>(xh + offB);

        const v2f va2 = {va, va}, vb2 = {vb, vb};
        a0 += va2 * __builtin_amdgcn_cvt_pk_f32_fp8((int)wa, false);
        a1 += va2 * __builtin_amdgcn_cvt_pk_f32_fp8((int)wa, true);
        a0 += vb2 * __builtin_amdgcn_cvt_pk_f32_fp8((int)wb, false);
        a1 += vb2 * __builtin_amdgcn_cvt_pk_f32_fp8((int)wb, true);
    }

    // reduce across the 8 edge groups
    float f0 = a0[0], f1 = a0[1], f2 = a1[0], f3 = a1[1];
#define RED(x) x += __shfl_xor(x, 8); x += __shfl_xor(x, 16); x += __shfl_xor(x, 32);
    RED(f0) RED(f1) RED(f2) RED(f3)
#undef RED
    const float s = 1.f / 1024.f;                 // undo x*16 and v*64
    f0 *= s; f1 *= s; f2 *= s; f3 *= s;

    if (g == 0) {
        const int o = (r << 6) + (H << 5) + (l << 2);   // f32 index
        if (MODE == 0) {
            *reinterpret_cast<float4*>(acc + o) = make_float4(f0, f1, f2, f3);
        } else if (MODE == 1) {
            float4 x0 = *reinterpret_cast<float4*>(acc + o);
            x0.x += f0; x0.y += f1; x0.z += f2; x0.w += f3;
            *reinterpret_cast<float4*>(acc + o) = x0;
        } else {
            const float* aep = (r < NUM_USER)
                ? user + ((size_t)r << 6) + (H << 5) + (l << 2)
                : item + ((size_t)(r - NUM_USER) << 6) + (H << 5) + (l << 2);
            const float4 ae = *reinterpret_cast<const float4*>(aep);
            const float4 x0 = *reinterpret_cast<const float4*>(acc + o);
            float4 lo;
            lo.x = (x0.x + f0 + ae.x) * 0.25f;
            lo.y = (x0.y + f1 + ae.y) * 0.25f;
            lo.z = (x0.z + f2 + ae.z) * 0.25f;
            lo.w = (x0.w + f3 + ae.w) * 0.25f;
            *reinterpret_cast<float4*>(out + o)      = lo;
            *reinterpret_cast<float4*>(out + ND + o) = ae;
        }
        if (MODE == 0 || MODE == 1) {
            destq[H * HWORDS + (r << 3) + l] =
                pk_fp8x4(f0 * 16.f, f1 * 16.f, f2 * 16.f, f3 * 16.f);
        }
    }
}

// ---------------- fallback (round-1 atomic path) ----------------

__global__ __launch_bounds__(256) void spmm_atomic(
    const float* __restrict__ vals, const int* __restrict__ rows,
    const int* __restrict__ cols, const float* __restrict__ x0,
    const float* __restrict__ x1, int split, float* __restrict__ out)
{
    const int lane = threadIdx.x & 63;
    const long wave   = ((long)blockIdx.x * blockDim.x + threadIdx.x) >> 6;
    const long nwaves = ((long)gridDim.x * blockDim.x) >> 6;
    for (long e = wave; e < NEDGE; e += nwaves) {
        const int   r = rows[e];
        const int   c = cols[e];
        const float v = vals[e];
        const float xv = (c < split) ? x0[(long)c * DIM + lane]
                                     : x1[(long)(c - split) * DIM + lane];
        atomicAdd(&out[(long)r * DIM + lane], v * xv);
    }
}

__global__ __launch_bounds__(256) void add2_kernel(
    const float* __restrict__ a, const float* __restrict__ b,
    float* __restrict__ acc)
{
    const int nvec = ND / 4;
    for (int i = blockIdx.x * blockDim.x + threadIdx.x; i < nvec;
         i += gridDim.x * blockDim.x) {
        const float4 av = ((const float4*)a)[i];
        const float4 bv = ((const float4*)b)[i];
        float4 o;
        o.x = av.x + bv.x; o.y = av.y + bv.y;
        o.z = av.z + bv.z; o.w = av.w + bv.w;
        ((float4*)acc)[i] = o;
    }
}

__global__ __launch_bounds__(256) void finalize3_kernel(
    const float* __restrict__ user, const float* __restrict__ item,
    float* __restrict__ out)
{
    const int nvec  = ND / 4;
    const int userv = NUM_USER * DIM / 4;
    for (int i = blockIdx.x * blockDim.x + threadIdx.x; i < nvec;
         i += gridDim.x * blockDim.x) {
        const float4 ae = (i < userv) ? ((const float4*)user)[i]
                                      : ((const float4*)item)[i - userv];
        const float4 ac = ((const float4*)out)[i];
        const float4 e3 = ((const float4*)(out + ND))[i];
        float4 lo;
        lo.x = (ae.x + ac.x + e3.x) * 0.25f;
        lo.y = (ae.y + ac.y + e3.y) * 0.25f;
        lo.z = (ae.z + ac.z + e3.z) * 0.25f;
        lo.w = (ae.w + ac.w + e3.w) * 0.25f;
        ((float4*)out)[i] = lo;
        ((float4*)(out + ND))[i] = ae;
    }
}

// ---------------- launch ----------------

extern "C" void kernel_launch(void* const* d_in, const int* in_sizes, int n_in,
                              void* d_out, int out_size, void* d_ws, size_t ws_size,
                              hipStream_t stream) {
    const float* user = (const float*)d_in[0];
    const float* item = (const float*)d_in[1];
    const float* vals = (const float*)d_in[2];
    const int*   rows = (const int*)d_in[3];
    const int*   cols = (const int*)d_in[4];

    float* out = (float*)d_out;
    float* acc = out;

    char* w = (char*)d_ws;
    unsigned char* xq0 = (unsigned char*)w;                         // ND fp8
    unsigned char* xq1 = xq0 + ND;                                  // ND fp8
    unsigned*      crG = (unsigned*)(xq1 + ND);                     // NB*CAP u32
    int*   rowbeg = (int*)(crG + (size_t)NB * CAP);
    int*   rowend = rowbeg + NTOT;
    int*   cursor = rowend + NTOT;
    unsigned short* vbG = (unsigned short*)(cursor + NB);           // NB*CAP u16
    const size_t ws_need = (size_t)ND * 2 + (size_t)NB * CAP * 6
                         + (size_t)(2 * NTOT + NB) * 4 + 64;

    if (ws_size >= ws_need) {
        hipMemsetAsync(cursor, 0, (size_t)NB * 4, stream);
        phaseA_kernel<<<NCHUNK + CVTB, 256, 0, stream>>>(
            rows, cols, vals, cursor, crG, vbG, user, item, (unsigned*)xq0);
        phaseB_kernel<<<NB, 256, 0, stream>>>(cursor, crG, vbG, rowbeg, rowend);

        const int spmm_blocks = NTOT / 4;   // 1 wave/row
        // layer 1
        spmm_pull<0,0><<<spmm_blocks, 256, 0, stream>>>(rowbeg, rowend, crG,
            xq0, (unsigned*)xq1, acc, nullptr, nullptr, nullptr);
        spmm_pull<0,1><<<spmm_blocks, 256, 0, stream>>>(rowbeg, rowend, crG,
            xq0, (unsigned*)xq1, acc, nullptr, nullptr, nullptr);
        // layer 2
        spmm_pull<1,0><<<spmm_blocks, 256, 0, stream>>>(rowbeg, rowend, crG,
            xq1, (unsigned*)xq0, acc, nullptr, nullptr, nullptr);
        spmm_pull<1,1><<<spmm_blocks, 256, 0, stream>>>(rowbeg, rowend, crG,
            xq1, (unsigned*)xq0, acc, nullptr, nullptr, nullptr);
        // layer 3 + finalize
        spmm_pull<2,0><<<spmm_blocks, 256, 0, stream>>>(rowbeg, rowend, crG,
            xq0, nullptr, acc, user, item, out);
        spmm_pull<2,1><<<spmm_blocks, 256, 0, stream>>>(rowbeg, rowend, crG,
            xq0, nullptr, acc, user, item, out);
    } else {
        float* bufA = (float*)d_ws;
        float* out1 = out + ND;
        const size_t nd_bytes = (size_t)ND * sizeof(float);
        hipMemsetAsync(out1, 0, nd_bytes, stream);
        spmm_atomic<<<2048, 256, 0, stream>>>(vals, rows, cols, user, item, NUM_USER, out1);
        hipMemsetAsync(bufA, 0, nd_bytes, stream);
        spmm_atomic<<<2048, 256, 0, stream>>>(vals, rows, cols, out1, out1, NTOT, bufA);
        add2_kernel<<<2048, 256, 0, stream>>>(out1, bufA, acc);
        hipMemsetAsync(out1, 0, nd_bytes, stream);
        spmm_atomic<<<2048, 256, 0, stream>>>(vals, rows, cols, bufA, bufA, NTOT, out1);
        finalize3_kernel<<<2048, 256, 0, stream>>>(user, item, out);
    }
}

// Round 11
// 273.253 us; speedup vs baseline: 2.7087x; 1.2310x over previous
//
#include <hip/hip_runtime.h>

// LightGCN single forward, round 11 (= round 10 with NT builtins on
// ext_vector types instead of HIP_vector_type float4/uint2).
// R7 structure + non-temporal hints on ALL streaming traffic in the SpMM
// (metadata, acc, dest, outputs); only the fp8 table gathers stay cacheable.
//
// d_out: [0,ND) light_out (acc until layer 3), [ND,2ND) user‖item copies.

#define NUM_USER 100000
#define NUM_ITEM 50000
#define NTOT     150000
#define DIM      64
#define NEDGE    2400000
#define ND       (NTOT * DIM)

#define RPB    256                       // rows per bucket
#define NB     586                       // ceil(NTOT/RPB)
#define CAP    4736                      // slots/bucket: mean 4096 + 10 sigma
#define CHUNK  4096                      // edges per phaseA block
#define NCHUNK 586                       // ceil(NEDGE/CHUNK)
#define EPT    16                        // CHUNK/256
#define CVTB   1024                      // extra phaseA blocks doing f32->fp8

typedef float    v2f __attribute__((ext_vector_type(2)));
typedef float    v4f __attribute__((ext_vector_type(4)));
typedef unsigned v2u __attribute__((ext_vector_type(2)));

// 4 f32 -> packed 4×fp8 e4m3 (HW RNE, saturating)
static __device__ __forceinline__ unsigned pk_fp8x4(float a, float b, float c, float d) {
    int p = 0;
    p = __builtin_amdgcn_cvt_pk_fp8_f32(a, b, p, false);
    p = __builtin_amdgcn_cvt_pk_fp8_f32(c, d, p, true);
    return (unsigned)p;
}
static __device__ __forceinline__ unsigned char f2fp8(float a) {
    return (unsigned char)(__builtin_amdgcn_cvt_pk_fp8_f32(a, 0.f, 0, false) & 0xFF);
}
// decode low byte of word -> f32
static __device__ __forceinline__ float fp8lo2f(unsigned w) {
    const v2f t = __builtin_amdgcn_cvt_pk_f32_fp8((int)w, false);
    return t[0];
}

// ---- Phase A: bin edges into 586 row-buckets; blocks >= NCHUNK convert
//      the f32 embeddings to the fp8(16x) x-table (independent, overlapped) ----
__global__ __launch_bounds__(256) void phaseA_kernel(
    const int*   __restrict__ rows,
    const int*   __restrict__ cols,
    const float* __restrict__ vals,
    int*            __restrict__ cursor,  // per-bucket fill count (memset 0)
    unsigned*       __restrict__ crG,     // packed (rowlow8<<18)|col18, bucketed
    unsigned short* __restrict__ vbG,     // fp8(64*val) in low byte, bucketed
    const float*    __restrict__ user,
    const float*    __restrict__ item,
    unsigned*       __restrict__ xq)      // fp8 table as u32 words
{
    __shared__ unsigned       s_cr[CHUNK];
    __shared__ unsigned short s_vb[CHUNK];
    __shared__ unsigned short s_bk[CHUNK];
    __shared__ int s_hist[NB];
    __shared__ int s_scan[NB];
    __shared__ int s_dst[NB];
    __shared__ int s_cur[NB];
    __shared__ int s_part[256];

    if (blockIdx.x >= NCHUNK) {
        // fused convert: all_emb (f32) -> fp8(16*x) table (u32 = 4 dims)
        const int nvec  = ND / 4;
        const int userv = NUM_USER * DIM / 4;
        for (int i = (blockIdx.x - NCHUNK) * 256 + threadIdx.x; i < nvec;
             i += CVTB * 256) {
            const float4 v = (i < userv) ? ((const float4*)user)[i]
                                         : ((const float4*)item)[i - userv];
            xq[i] = pk_fp8x4(v.x * 16.f, v.y * 16.f, v.z * 16.f, v.w * 16.f);
        }
        return;
    }

    const int t    = threadIdx.x;
    const int base = blockIdx.x * CHUNK;
    const int n    = min(CHUNK, NEDGE - base);

    for (int i = t; i < NB; i += 256) s_hist[i] = 0;
    __syncthreads();

    int            mrow[EPT];
    unsigned       mcol[EPT];
    unsigned short mvb[EPT];
#pragma unroll
    for (int k = 0; k < EPT; ++k) {
        const int i = t + k * 256;
        if (i < n) {
            const int e = base + i;
            mrow[k] = rows[e];
            mcol[k] = (unsigned)cols[e];
            mvb[k]  = f2fp8(vals[e] * 64.f);
            atomicAdd(&s_hist[mrow[k] >> 8], 1);
        } else mrow[k] = -1;
    }
    __syncthreads();

    // exclusive scan of s_hist[0..NB)
    int loc[3]; int ssum = 0;
#pragma unroll
    for (int k = 0; k < 3; ++k) {
        const int i = t * 3 + k;
        loc[k] = (i < NB) ? s_hist[i] : 0;
        ssum += loc[k];
    }
    s_part[t] = ssum;
    __syncthreads();
    for (int o = 1; o < 256; o <<= 1) {
        const int v = (t >= o) ? s_part[t - o] : 0;
        __syncthreads();
        s_part[t] += v;
        __syncthreads();
    }
    int run = s_part[t] - ssum;
#pragma unroll
    for (int k = 0; k < 3; ++k) {
        const int i = t * 3 + k;
        if (i < NB) { s_scan[i] = run; run += loc[k]; }
    }
    __syncthreads();

    for (int i = t; i < NB; i += 256) {
        const int c = s_hist[i];
        s_dst[i] = i * CAP + (c ? atomicAdd(&cursor[i], c) : 0);
        s_cur[i] = s_scan[i];
    }
    __syncthreads();

#pragma unroll
    for (int k = 0; k < EPT; ++k) {
        if (mrow[k] >= 0) {
            const int b   = mrow[k] >> 8;
            const int pos = atomicAdd(&s_cur[b], 1);
            s_cr[pos] = mcol[k] | ((unsigned)(mrow[k] & 255) << 18);
            s_vb[pos] = mvb[k];
            s_bk[pos] = (unsigned short)b;
        }
    }
    __syncthreads();

    for (int p = t; p < n; p += 256) {
        const int b = s_bk[p];
        const int g = s_dst[b] + (p - s_scan[b]);
        crG[g] = s_cr[p];
        vbG[g] = s_vb[p];
    }
}

// ---- Phase B: per-bucket in-LDS counting sort by row; writeback converts
//      to the SpMM format (col<<8)|fp8val; emit rowbeg/rowend ----
__global__ __launch_bounds__(256) void phaseB_kernel(
    const int*      __restrict__ cursor,
    unsigned*       __restrict__ crG,
    const unsigned short* __restrict__ vbG,
    int*            __restrict__ rowbeg,
    int*            __restrict__ rowend)
{
    __shared__ unsigned       s_cr[CAP];
    __shared__ unsigned short s_vb[CAP];
    __shared__ unsigned short s_idx[CAP];
    __shared__ int s_hist[RPB];
    __shared__ int s_scan[RPB];
    __shared__ int s_cur[RPB];

    const int b = blockIdx.x, t = threadIdx.x;
    const int gbase = b * CAP;
    const int cnt = cursor[b];

    s_hist[t] = 0;
    __syncthreads();
    for (int p = t; p < cnt; p += 256) {
        const unsigned cr = crG[gbase + p];
        s_cr[p] = cr;
        s_vb[p] = vbG[gbase + p];
        atomicAdd(&s_hist[cr >> 18], 1);
    }
    __syncthreads();

    const int h = s_hist[t];
    s_scan[t] = h;
    __syncthreads();
    for (int o = 1; o < 256; o <<= 1) {
        const int v = (t >= o) ? s_scan[t - o] : 0;
        __syncthreads();
        s_scan[t] += v;
        __syncthreads();
    }
    const int excl = s_scan[t] - h;
    s_cur[t] = excl;
    __syncthreads();

    for (int p = t; p < cnt; p += 256) {
        const int r   = s_cr[p] >> 18;
        const int pos = atomicAdd(&s_cur[r], 1);
        s_idx[pos] = (unsigned short)p;
    }
    __syncthreads();

    for (int p = t; p < cnt; p += 256) {
        const int i = s_idx[p];
        // SpMM metadata format: (col18 << 8) | fp8(64*val)
        crG[gbase + p] = ((s_cr[i] & 0x3FFFFu) << 8) | (unsigned)(s_vb[i] & 0xFFu);
    }
    const int row = b * RPB + t;
    if (row < NTOT) {
        rowbeg[row] = gbase + excl;
        rowend[row] = gbase + excl + h;
    }
}

// ---- pull SpMM: one wave/row, 8 edge groups × 2-deep unroll.
//      Lane reads 8 fp8 dims (dwordx2); one u32 metadata load per edge.
//      All streaming traffic is non-temporal; only xq gathers are cached.
// MODE 0: acc=res, destq=fp8(16*res)
// MODE 1: acc+=res, destq=fp8(16*res)
// MODE 2: light_out=(acc+res+ae)/4, out2=ae   (finalize fused)
template<int MODE>
__global__ __launch_bounds__(256) void spmm_pull(
    const int*            __restrict__ rowbeg,
    const int*            __restrict__ rowend,
    const unsigned*       __restrict__ cv,      // (col<<8)|fp8v
    const unsigned char*  __restrict__ xq,      // fp8 table (row = 64 B)
    unsigned*             __restrict__ destq,   // fp8 out (u32 words)
    float*                __restrict__ acc,
    const float*          __restrict__ user,
    const float*          __restrict__ item,
    float*                __restrict__ out)
{
    const int r    = (blockIdx.x * 256 + threadIdx.x) >> 6;  // grid sized exactly
    const int lane = threadIdx.x & 63;
    const int g    = lane >> 3;          // edge group 0..7
    const int l    = lane & 7;           // lane-in-group: dims 8l..8l+7

    const int beg = __builtin_amdgcn_readfirstlane(rowbeg[r]);
    const int end = __builtin_amdgcn_readfirstlane(rowend[r]);

    v2f a0 = {0.f,0.f}, a1 = {0.f,0.f}, a2 = {0.f,0.f}, a3 = {0.f,0.f};
    for (int k = beg + g; k < end; k += 16) {
        const bool h1 = (k + 8) < end;
        const int  kb = h1 ? k + 8 : k;          // clamped: always valid
        const unsigned ca = __builtin_nontemporal_load(cv + k);
        unsigned cb = __builtin_nontemporal_load(cv + kb);
        cb = h1 ? cb : (cb & ~0xFFu);            // zero val byte on tail

        const float va = fp8lo2f(ca);
        const float vb = fp8lo2f(cb);

        const unsigned offA = ((ca & 0xFFFFFF00u) >> 2) + (l << 3);  // col*64+l*8
        const unsigned offB = ((cb & 0xFFFFFF00u) >> 2) + (l << 3);
        const v2u wa = *reinterpret_cast<const v2u*>(xq + offA);     // cached
        const v2u wb = *reinterpret_cast<const v2u*>(xq + offB);     // cached

        const v2f va2 = {va, va}, vb2 = {vb, vb};
        a0 += va2 * __builtin_amdgcn_cvt_pk_f32_fp8((int)wa[0], false);
        a1 += va2 * __builtin_amdgcn_cvt_pk_f32_fp8((int)wa[0], true);
        a2 += va2 * __builtin_amdgcn_cvt_pk_f32_fp8((int)wa[1], false);
        a3 += va2 * __builtin_amdgcn_cvt_pk_f32_fp8((int)wa[1], true);
        a0 += vb2 * __builtin_amdgcn_cvt_pk_f32_fp8((int)wb[0], false);
        a1 += vb2 * __builtin_amdgcn_cvt_pk_f32_fp8((int)wb[0], true);
        a2 += vb2 * __builtin_amdgcn_cvt_pk_f32_fp8((int)wb[1], false);
        a3 += vb2 * __builtin_amdgcn_cvt_pk_f32_fp8((int)wb[1], true);
    }

    // reduce across the 8 edge groups (lanes with same l share dims)
    float f0 = a0[0], f1 = a0[1], f2 = a1[0], f3 = a1[1];
    float f4 = a2[0], f5 = a2[1], f6 = a3[0], f7 = a3[1];
#define RED(x) x += __shfl_xor(x, 8); x += __shfl_xor(x, 16); x += __shfl_xor(x, 32);
    RED(f0) RED(f1) RED(f2) RED(f3) RED(f4) RED(f5) RED(f6) RED(f7)
#undef RED
    const float s = 1.f / 1024.f;                 // undo x*16 and v*64
    f0 *= s; f1 *= s; f2 *= s; f3 *= s; f4 *= s; f5 *= s; f6 *= s; f7 *= s;

    if (g == 0) {
        const int o = r * DIM + (l << 3);         // lane l: dims 8l..8l+7
        if (MODE == 0) {
            __builtin_nontemporal_store((v4f){f0, f1, f2, f3},
                                        reinterpret_cast<v4f*>(acc + o));
            __builtin_nontemporal_store((v4f){f4, f5, f6, f7},
                                        reinterpret_cast<v4f*>(acc + o + 4));
        } else if (MODE == 1) {
            v4f x0 = __builtin_nontemporal_load(
                         reinterpret_cast<const v4f*>(acc + o));
            v4f x1 = __builtin_nontemporal_load(
                         reinterpret_cast<const v4f*>(acc + o + 4));
            x0 += (v4f){f0, f1, f2, f3};
            x1 += (v4f){f4, f5, f6, f7};
            __builtin_nontemporal_store(x0, reinterpret_cast<v4f*>(acc + o));
            __builtin_nontemporal_store(x1, reinterpret_cast<v4f*>(acc + o + 4));
        } else {
            const float* aep = (r < NUM_USER)
                ? user + (size_t)r * DIM + (l << 3)
                : item + (size_t)(r - NUM_USER) * DIM + (l << 3);
            const v4f e0 = __builtin_nontemporal_load(
                               reinterpret_cast<const v4f*>(aep));
            const v4f e1 = __builtin_nontemporal_load(
                               reinterpret_cast<const v4f*>(aep + 4));
            const v4f x0 = __builtin_nontemporal_load(
                               reinterpret_cast<const v4f*>(acc + o));
            const v4f x1 = __builtin_nontemporal_load(
                               reinterpret_cast<const v4f*>(acc + o + 4));
            const v4f lo0 = (x0 + (v4f){f0, f1, f2, f3} + e0) * 0.25f;
            const v4f lo1 = (x1 + (v4f){f4, f5, f6, f7} + e1) * 0.25f;
            __builtin_nontemporal_store(lo0, reinterpret_cast<v4f*>(out + o));
            __builtin_nontemporal_store(lo1, reinterpret_cast<v4f*>(out + o + 4));
            __builtin_nontemporal_store(e0, reinterpret_cast<v4f*>(out + ND + o));
            __builtin_nontemporal_store(e1, reinterpret_cast<v4f*>(out + ND + o + 4));
        }
        if (MODE == 0 || MODE == 1) {
            v2u pk;
            pk[0] = pk_fp8x4(f0 * 16.f, f1 * 16.f, f2 * 16.f, f3 * 16.f);
            pk[1] = pk_fp8x4(f4 * 16.f, f5 * 16.f, f6 * 16.f, f7 * 16.f);
            __builtin_nontemporal_store(pk,
                reinterpret_cast<v2u*>(destq + (r << 4) + (l << 1)));
        }
    }
}

// ---------------- fallback (round-1 atomic path) ----------------

__global__ __launch_bounds__(256) void spmm_atomic(
    const float* __restrict__ vals, const int* __restrict__ rows,
    const int* __restrict__ cols, const float* __restrict__ x0,
    const float* __restrict__ x1, int split, float* __restrict__ out)
{
    const int lane = threadIdx.x & 63;
    const long wave   = ((long)blockIdx.x * blockDim.x + threadIdx.x) >> 6;
    const long nwaves = ((long)gridDim.x * blockDim.x) >> 6;
    for (long e = wave; e < NEDGE; e += nwaves) {
        const int   r = rows[e];
        const int   c = cols[e];
        const float v = vals[e];
        const float xv = (c < split) ? x0[(long)c * DIM + lane]
                                     : x1[(long)(c - split) * DIM + lane];
        atomicAdd(&out[(long)r * DIM + lane], v * xv);
    }
}

__global__ __launch_bounds__(256) void add2_kernel(
    const float* __restrict__ a, const float* __restrict__ b,
    float* __restrict__ acc)
{
    const int nvec = ND / 4;
    for (int i = blockIdx.x * blockDim.x + threadIdx.x; i < nvec;
         i += gridDim.x * blockDim.x) {
        const float4 av = ((const float4*)a)[i];
        const float4 bv = ((const float4*)b)[i];
        float4 o;
        o.x = av.x + bv.x; o.y = av.y + bv.y;
        o.z = av.z + bv.z; o.w = av.w + bv.w;
        ((float4*)acc)[i] = o;
    }
}

__global__ __launch_bounds__(256) void finalize3_kernel(
    const float* __restrict__ user, const float* __restrict__ item,
    float* __restrict__ out)
{
    const int nvec  = ND / 4;
    const int userv = NUM_USER * DIM / 4;
    for (int i = blockIdx.x * blockDim.x + threadIdx.x; i < nvec;
         i += gridDim.x * blockDim.x) {
        const float4 ae = (i < userv) ? ((const float4*)user)[i]
                                      : ((const float4*)item)[i - userv];
        const float4 ac = ((const float4*)out)[i];
        const float4 e3 = ((const float4*)(out + ND))[i];
        float4 lo;
        lo.x = (ae.x + ac.x + e3.x) * 0.25f;
        lo.y = (ae.y + ac.y + e3.y) * 0.25f;
        lo.z = (ae.z + ac.z + e3.z) * 0.25f;
        lo.w = (ae.w + ac.w + e3.w) * 0.25f;
        ((float4*)out)[i] = lo;
        ((float4*)(out + ND))[i] = ae;
    }
}

// ---------------- launch ----------------

extern "C" void kernel_launch(void* const* d_in, const int* in_sizes, int n_in,
                              void* d_out, int out_size, void* d_ws, size_t ws_size,
                              hipStream_t stream) {
    const float* user = (const float*)d_in[0];
    const float* item = (const float*)d_in[1];
    const float* vals = (const float*)d_in[2];
    const int*   rows = (const int*)d_in[3];
    const int*   cols = (const int*)d_in[4];

    float* out = (float*)d_out;
    float* acc = out;

    char* w = (char*)d_ws;
    unsigned char* xq0 = (unsigned char*)w;                         // ND fp8
    unsigned char* xq1 = xq0 + ND;                                  // ND fp8
    unsigned*      crG = (unsigned*)(xq1 + ND);                     // NB*CAP u32
    int*   rowbeg = (int*)(crG + (size_t)NB * CAP);
    int*   rowend = rowbeg + NTOT;
    int*   cursor = rowend + NTOT;
    unsigned short* vbG = (unsigned short*)(cursor + NB);           // NB*CAP u16
    const size_t ws_need = (size_t)ND * 2 + (size_t)NB * CAP * 6
                         + (size_t)(2 * NTOT + NB) * 4 + 64;

    if (ws_size >= ws_need) {
        hipMemsetAsync(cursor, 0, (size_t)NB * 4, stream);
        phaseA_kernel<<<NCHUNK + CVTB, 256, 0, stream>>>(
            rows, cols, vals, cursor, crG, vbG, user, item, (unsigned*)xq0);
        phaseB_kernel<<<NB, 256, 0, stream>>>(cursor, crG, vbG, rowbeg, rowend);

        const int spmm_blocks = NTOT / 4;   // 1 wave/row
        spmm_pull<0><<<spmm_blocks, 256, 0, stream>>>(rowbeg, rowend, crG,
            xq0, (unsigned*)xq1, acc, nullptr, nullptr, nullptr);    // emb1
        spmm_pull<1><<<spmm_blocks, 256, 0, stream>>>(rowbeg, rowend, crG,
            xq1, (unsigned*)xq0, acc, nullptr, nullptr, nullptr);    // emb2
        spmm_pull<2><<<spmm_blocks, 256, 0, stream>>>(rowbeg, rowend, crG,
            xq0, nullptr, acc, user, item, out);                     // emb3+finalize
    } else {
        float* bufA = (float*)d_ws;
        float* out1 = out + ND;
        const size_t nd_bytes = (size_t)ND * sizeof(float);
        hipMemsetAsync(out1, 0, nd_bytes, stream);
        spmm_atomic<<<2048, 256, 0, stream>>>(vals, rows, cols, user, item, NUM_USER, out1);
        hipMemsetAsync(bufA, 0, nd_bytes, stream);
        spmm_atomic<<<2048, 256, 0, stream>>>(vals, rows, cols, out1, out1, NTOT, bufA);
        add2_kernel<<<2048, 256, 0, stream>>>(out1, bufA, acc);
        hipMemsetAsync(out1, 0, nd_bytes, stream);
        spmm_atomic<<<2048, 256, 0, stream>>>(vals, rows, cols, bufA, bufA, NTOT, out1);
        finalize3_kernel<<<2048, 256, 0, stream>>>(user, item, out);
    }
}